// Round 11
// baseline (214.610 us; speedup 1.0000x reference)
//
#include <hip/hip_runtime.h>

typedef unsigned short u16;
typedef unsigned int u32;

#define N_NODES 100000
#define N_EDGES 50000
#define C 128
#define G_CHUNK 1563              // ceil(100000/64) 64-row chunks
#define GEMM_BLOCKS 512           // 2 blocks/CU exactly (64KB LDS each)
#define NCNT (N_EDGES + N_NODES)  // 150000 combined key space (edges then nodes)
#define NBUCKC 1172               // ceil(150000 / 128) coarse buckets (key>>7)
#define BCHUNK 2048               // incidences per bucketize block

static __device__ __forceinline__ float bf2f(u16 h) {
    u32 u = ((u32)h) << 16;
    float f;
    __builtin_memcpy(&f, &u, 4);
    return f;
}

static __device__ __forceinline__ u16 f2bf(float f) {
    u32 u;
    __builtin_memcpy(&u, &f, 4);
    return (u16)((u + 0x7fffu + ((u >> 16) & 1u)) >> 16);  // RNE
}

typedef short s16x8 __attribute__((ext_vector_type(8)));
typedef float f32x4 __attribute__((ext_vector_type(4)));

// ---------------- prep: W transpose (blocks 0-63) + bucket hist (64..) -----
// Independent work fused into one launch (saves a graph launch gap).
__global__ __launch_bounds__(256) void prep_k(
    const float* __restrict__ W, u16* __restrict__ Wt,
    const int* __restrict__ ni, const int* __restrict__ ei,
    u32* __restrict__ cntM, int nnz, int nb1) {
    __shared__ u32 h[NBUCKC];
    if (blockIdx.x < 64) {
        int idx = blockIdx.x * 256 + threadIdx.x;  // 16384 total
        int k = idx >> 7, oc = idx & 127;
        Wt[oc * 128 + k] = f2bf(W[k * 128 + oc]);
        return;
    }
    int blk = blockIdx.x - 64;
    for (int b = threadIdx.x; b < NBUCKC; b += 256) h[b] = 0;
    __syncthreads();
    int i0 = blk * BCHUNK;
    int iend = min(i0 + BCHUNK, nnz);
    for (int i = i0 + threadIdx.x; i < iend; i += 256) {
        int e = ei[i], n = ni[i];
        atomicAdd(&h[e >> 7], 1u);                 // LDS atomic (fast)
        atomicAdd(&h[(N_EDGES + n) >> 7], 1u);
    }
    __syncthreads();
    for (int b = threadIdx.x; b < NBUCKC; b += 256)
        cntM[(size_t)b * nb1 + blk] = h[b];        // plain stores
}

// ---------------- GEMM: double-buffered 2-phase pipeline (r11) -------------
// r10 post-mortem: six GEMM variants all ~42us @1.2TB/s (12us floor) -> the
// common structure is the CONVOY: one-shot blocks burst 32KB of DMA, drain
// it fully at a barrier, compute, die; memory idle during compute and vice
// versa. Fix (catalog T3-lite): 512 persistent-ish blocks (2/CU), 2x32KB LDS,
// prefetch next chunk then wait vmcnt(8) (counted - next's 8 loads STAY IN
// FLIGHT across both raw s_barriers; __syncthreads would drain vmcnt(0)).
// sched_barrier(0) fences stop hipcc sinking ds_reads past barrier#2 (rule
// #18 hoist hazard / cross-wave race with next STAGE).
// xw[n][oc] = x[n][:] . W[:][oc], bf16 out. One wave per 16-row tile;
// A[m=lane&15][k=quad*8+j]; D col=lane&15, row=quad*4+reg (verified m89/m91).
__global__ __launch_bounds__(256) void gemm_k(
    const float* __restrict__ x, const u16* __restrict__ Wt,
    u16* __restrict__ xw) {
    __shared__ __align__(16) float xs[2][64 * C];  // 2 x 32 KB
    const int tid = threadIdx.x;
    const int lane = tid & 63;
    const int wave = tid >> 6;
    const int blk = blockIdx.x;

    // stage chunk c (64 rows) into buffer b: 8 gload_lds x 16B per wave.
    // LDS dest = wave-uniform base + lane*16 (HW rule); per-lane global src;
    // tail rows redirected to x[0] (their tiles are store-guarded).
    auto STAGE = [&](int c, int b) {
        size_t gbase = (size_t)c * 64 * C;
#pragma unroll
        for (int rnd = 0; rnd < 8; ++rnd) {
            int fl = rnd * 1024 + wave * 256 + lane * 4;
            int grow = c * 64 + (fl >> 7);
            const float* src = (grow < N_NODES) ? (x + gbase + fl) : x;
            __builtin_amdgcn_global_load_lds(
                (const __attribute__((address_space(1))) void*)src,
                (__attribute__((address_space(3))) void*)(&xs[b][rnd * 1024 + wave * 256]),
                16, 0, 0);
        }
    };

    STAGE(blk, 0);
    int it = 0;
    for (int c = blk; c < G_CHUNK; c += GEMM_BLOCKS, ++it) {
        const int cb = it & 1;
        const int cn = c + GEMM_BLOCKS;
        if (cn < G_CHUNK) STAGE(cn, cb ^ 1);  // writes buf read at it-1 (see #2)
        __builtin_amdgcn_sched_barrier(0);
        // wait cur chunk's 8 loads (oldest); leave next chunk's 8 in flight.
        // (prev iter's B-loads/stores are older than next-stage -> also forced
        //  retired; harmless.)
        asm volatile("s_waitcnt vmcnt(8)" ::: "memory");
        __builtin_amdgcn_s_barrier();  // #1: cur buf fully staged (all waves)
        __builtin_amdgcn_sched_barrier(0);

        const int tile = c * 4 + wave;
        const int m = lane & 15;
        const int quad = lane >> 4;
        const bool live = (tile < 6250);  // 100000 = 6250*16 exactly

        union { uint4 u; s16x8 v; } a[4];
        if (live) {
            const float* xr = &xs[cb][(wave * 16 + m) * C + quad * 8];
#pragma unroll
            for (int kk = 0; kk < 4; ++kk) {
                float4 v0 = *(const float4*)(xr + kk * 32);
                float4 v1 = *(const float4*)(xr + kk * 32 + 4);
                a[kk].u.x = (u32)f2bf(v0.x) | ((u32)f2bf(v0.y) << 16);
                a[kk].u.y = (u32)f2bf(v0.z) | ((u32)f2bf(v0.w) << 16);
                a[kk].u.z = (u32)f2bf(v1.x) | ((u32)f2bf(v1.y) << 16);
                a[kk].u.w = (u32)f2bf(v1.z) | ((u32)f2bf(v1.w) << 16);
            }
        }
        __builtin_amdgcn_sched_barrier(0);  // keep ds_reads ABOVE barrier#2
        __builtin_amdgcn_s_barrier();  // #2: all waves done reading cur buf
        __builtin_amdgcn_sched_barrier(0);

        if (live) {
            f32x4 acc[8];
#pragma unroll
            for (int nt = 0; nt < 8; ++nt) acc[nt] = (f32x4){0.f, 0.f, 0.f, 0.f};
#pragma unroll
            for (int kk = 0; kk < 4; ++kk) {
                int kb = kk * 32 + quad * 8;
#pragma unroll
                for (int nt = 0; nt < 8; ++nt) {
                    union { uint4 u; s16x8 v; } b;
                    b.u = *(const uint4*)(Wt + (size_t)(nt * 16 + m) * C + kb);
                    acc[nt] = __builtin_amdgcn_mfma_f32_16x16x32_bf16(
                        a[kk].v, b.v, acc[nt], 0, 0, 0);
                }
            }
            int row0 = tile * 16;
#pragma unroll
            for (int nt = 0; nt < 8; ++nt)
#pragma unroll
                for (int r = 0; r < 4; ++r)
                    xw[(size_t)(row0 + quad * 4 + r) * C + nt * 16 + m] =
                        f2bf(acc[nt][r]);
        }
    }
}

// ---------------- scan A: generic exclusive scan ---------------------------
__global__ __launch_bounds__(256) void scan_a2(const u32* __restrict__ cnt,
                                               u32* __restrict__ off,
                                               u32* __restrict__ bsum, int N) {
    __shared__ u32 wsum[4];
    int tid = threadIdx.x;
    int base = blockIdx.x * 1024 + tid * 4;
    u32 v0 = 0, v1 = 0, v2 = 0, v3 = 0;
    if (base + 3 < N) {
        uint4 v = *(const uint4*)(cnt + base);
        v0 = v.x; v1 = v.y; v2 = v.z; v3 = v.w;
    } else {
        if (base + 0 < N) v0 = cnt[base + 0];
        if (base + 1 < N) v1 = cnt[base + 1];
        if (base + 2 < N) v2 = cnt[base + 2];
        if (base + 3 < N) v3 = cnt[base + 3];
    }
    u32 s = v0 + v1 + v2 + v3;
    int lane = tid & 63, wv = tid >> 6;
    u32 x = s;
    for (int d = 1; d < 64; d <<= 1) {
        u32 y = __shfl_up(x, (unsigned)d);
        if (lane >= d) x += y;
    }
    if (lane == 63) wsum[wv] = x;
    __syncthreads();
    u32 wo = 0;
    for (int w = 0; w < 4; ++w) wo += (w < wv) ? wsum[w] : 0u;
    u32 ex = wo + x - s;
    if (base + 0 < N) off[base + 0] = ex;
    if (base + 1 < N) off[base + 1] = ex + v0;
    if (base + 2 < N) off[base + 2] = ex + v0 + v1;
    if (base + 3 < N) off[base + 3] = ex + v0 + v1 + v2;
    if (tid == 255) bsum[blockIdx.x] = wo + x;  // block total
}

// ---------------- scan B: exclusive scan of up to 512 block sums ----------
__global__ __launch_bounds__(256) void scan_b2(u32* __restrict__ bsum, int nb) {
    __shared__ u32 wsum[4];
    int t = threadIdx.x;
    u32 v0 = (2 * t < nb) ? bsum[2 * t] : 0u;
    u32 v1 = (2 * t + 1 < nb) ? bsum[2 * t + 1] : 0u;
    u32 s = v0 + v1;
    int lane = t & 63, wv = t >> 6;
    u32 x = s;
    for (int d = 1; d < 64; d <<= 1) {
        u32 y = __shfl_up(x, (unsigned)d);
        if (lane >= d) x += y;
    }
    if (lane == 63) wsum[wv] = x;
    __syncthreads();
    u32 wo = 0;
    for (int w = 0; w < 4; ++w) wo += (w < wv) ? wsum[w] : 0u;
    u32 ex = wo + x - s;
    if (2 * t < nb) bsum[2 * t] = ex;
    if (2 * t + 1 < nb) bsum[2 * t + 1] = ex + v0;
}

// ---------------- place entries bucket-grouped (LDS cursors only) ----------
__global__ __launch_bounds__(256) void bucket_place_k(
    const int* __restrict__ ni, const int* __restrict__ ei,
    const u32* __restrict__ offM, const u32* __restrict__ bsum,
    u32* __restrict__ stage, int nnz, int nb1) {
    __shared__ u32 cur[NBUCKC];
    for (int b = threadIdx.x; b < NBUCKC; b += 256) {
        size_t idx = (size_t)b * nb1 + blockIdx.x;
        cur[b] = offM[idx] + bsum[idx >> 10];
    }
    __syncthreads();
    int i0 = blockIdx.x * BCHUNK;
    int iend = min(i0 + BCHUNK, nnz);
    for (int i = i0 + threadIdx.x; i < iend; i += 256) {
        int e = ei[i], n = ni[i];
        u32 p1 = atomicAdd(&cur[e >> 7], 1u);
        stage[p1] = ((u32)(e & 127) << 17) | (u32)n;
        int k2 = N_EDGES + n;
        u32 p2 = atomicAdd(&cur[k2 >> 7], 1u);
        stage[p2] = ((u32)(k2 & 127) << 17) | (u32)e;
    }
}

// ---------------- per-bucket fine counting-sort -> dense CSR + rowinfo -----
__global__ __launch_bounds__(256) void bucket_csr_k(
    const u32* __restrict__ offM, const u32* __restrict__ bsum,
    const u32* __restrict__ stage, u32* __restrict__ csr,
    uint2* __restrict__ rowinfo, int nnz, int nb1) {
    __shared__ u32 h[128];
    __shared__ u32 ks[128];
    int b = blockIdx.x;
    size_t i0 = (size_t)b * nb1;
    u32 gstart = offM[i0] + bsum[i0 >> 10];
    u32 gend;
    if (b + 1 < NBUCKC) {
        size_t i1 = (size_t)(b + 1) * nb1;
        gend = offM[i1] + bsum[i1 >> 10];
    } else {
        gend = (u32)(2 * nnz);
    }
    int size = (int)(gend - gstart);
    if (threadIdx.x < 128) h[threadIdx.x] = 0;
    __syncthreads();
    for (int i = threadIdx.x; i < size; i += 256)
        atomicAdd(&h[stage[gstart + i] >> 17], 1u);
    __syncthreads();
    if (threadIdx.x < 64) {
        int l = threadIdx.x;
        u32 s0 = h[2 * l], s1 = h[2 * l + 1];
        u32 ps = s0 + s1;
        u32 x = ps;
        for (int d = 1; d < 64; d <<= 1) {
            u32 y = __shfl_up(x, (unsigned)d);
            if (l >= d) x += y;
        }
        u32 ex = x - ps;  // exclusive pair prefix within bucket
        ks[2 * l] = ex;
        ks[2 * l + 1] = ex + s0;
        int gk = b * 128 + 2 * l;
        if (gk < NCNT) rowinfo[gk] = make_uint2(gstart + ex, s0);
        if (gk + 1 < NCNT) rowinfo[gk + 1] = make_uint2(gstart + ex + s0, s1);
    }
    __syncthreads();
    for (int i = threadIdx.x; i < size; i += 256) {
        u32 en = stage[gstart + i];
        u32 kl = en >> 17;
        u32 p = atomicAdd(&ks[kl], 1u);
        csr[gstart + p] = en & 0x1FFFFu;
    }
}

// ---------------- pair-row gather body (r10, unchanged) --------------------
// Lanes 0-31 read row of entry (t+2k), lanes 32-63 row of entry (t+2k+1),
// 8 B/lane: one load covers two entries. Halves merged by shfl_xor(32).
#define GATHERP(SRC)                                                          \
    for (u32 base = 0; base < deg; base += 64) {                              \
        int m = (int)min(64u, deg - base);                                    \
        int myidx = (lane < m) ? (int)csr[start + base + lane] : 0;           \
        for (int t = 0; t < m; t += 8) {                                      \
            int e0 = min(t + 0 + half, m - 1), e1 = min(t + 2 + half, m - 1); \
            int e2 = min(t + 4 + half, m - 1), e3 = min(t + 6 + half, m - 1); \
            int r0 = __shfl(myidx, e0), r1 = __shfl(myidx, e1);               \
            int r2 = __shfl(myidx, e2), r3 = __shfl(myidx, e3);               \
            uint2 u0 = ((const uint2*)(SRC + (size_t)r0 * C))[ch];            \
            uint2 u1 = ((const uint2*)(SRC + (size_t)r1 * C))[ch];            \
            uint2 u2 = ((const uint2*)(SRC + (size_t)r2 * C))[ch];            \
            uint2 u3 = ((const uint2*)(SRC + (size_t)r3 * C))[ch];            \
            float m0 = (t + 0 + half < m) ? 1.f : 0.f;                        \
            float m1 = (t + 2 + half < m) ? 1.f : 0.f;                        \
            float m2 = (t + 4 + half < m) ? 1.f : 0.f;                        \
            float m3 = (t + 6 + half < m) ? 1.f : 0.f;                        \
            a0 += m0 * bf2f((u16)(u0.x & 0xffffu)) + m1 * bf2f((u16)(u1.x & 0xffffu)) \
                + m2 * bf2f((u16)(u2.x & 0xffffu)) + m3 * bf2f((u16)(u3.x & 0xffffu)); \
            a1 += m0 * bf2f((u16)(u0.x >> 16)) + m1 * bf2f((u16)(u1.x >> 16)) \
                + m2 * bf2f((u16)(u2.x >> 16)) + m3 * bf2f((u16)(u3.x >> 16)); \
            a2 += m0 * bf2f((u16)(u0.y & 0xffffu)) + m1 * bf2f((u16)(u1.y & 0xffffu)) \
                + m2 * bf2f((u16)(u2.y & 0xffffu)) + m3 * bf2f((u16)(u3.y & 0xffffu)); \
            a3 += m0 * bf2f((u16)(u0.y >> 16)) + m1 * bf2f((u16)(u1.y >> 16)) \
                + m2 * bf2f((u16)(u2.y >> 16)) + m3 * bf2f((u16)(u3.y >> 16)); \
        }                                                                     \
    }                                                                         \
    a0 += __shfl_xor(a0, 32);                                                 \
    a1 += __shfl_xor(a1, 32);                                                 \
    a2 += __shfl_xor(a2, 32);                                                 \
    a3 += __shfl_xor(a3, 32);

// ---------------- edge gather over CSR: 1 edge per wave -------------------
__global__ __launch_bounds__(256) void edge_gather_k(const u16* __restrict__ xw,
                                                     const uint2* __restrict__ rowinfo,
                                                     const u32* __restrict__ csrC,
                                                     u16* __restrict__ ef) {
    int e = blockIdx.x * 4 + (threadIdx.x >> 6);
    if (e >= N_EDGES) return;
    int lane = threadIdx.x & 63;
    int half = lane >> 5, ch = lane & 31;
    uint2 ri = rowinfo[e];
    u32 deg = ri.y;
    u32 start = ri.x;  // absolute position in combined csr
    const u32* csr = csrC;
    float a0 = 0.f, a1 = 0.f, a2 = 0.f, a3 = 0.f;
    GATHERP(xw)
    float sc = deg ? 1.f / (float)deg : 0.f;
    if (lane < 32) {
        uint2 w;
        w.x = (u32)f2bf(a0 * sc) | ((u32)f2bf(a1 * sc) << 16);
        w.y = (u32)f2bf(a2 * sc) | ((u32)f2bf(a3 * sc) << 16);
        ((uint2*)(ef + (size_t)e * C))[ch] = w;
    }
}

// ---------------- node gather over CSR: 1 node per wave -------------------
__global__ __launch_bounds__(256) void node_gather_k(const u16* __restrict__ ef,
                                                     const uint2* __restrict__ rowinfo,
                                                     const u32* __restrict__ csrC,
                                                     const float* __restrict__ bias,
                                                     float* __restrict__ out) {
    int v = blockIdx.x * 4 + (threadIdx.x >> 6);
    if (v >= N_NODES) return;
    int lane = threadIdx.x & 63;
    int half = lane >> 5, ch = lane & 31;
    uint2 ri = rowinfo[N_EDGES + v];
    u32 deg = ri.y;
    u32 start = ri.x;
    const u32* csr = csrC;
    float a0 = 0.f, a1 = 0.f, a2 = 0.f, a3 = 0.f;
    GATHERP(ef)
    float sc = deg ? 1.f / (float)deg : 0.f;
    if (lane < 32) {
        float4 bv = *(const float4*)(bias + ch * 4);
        float4 w;
        w.x = a0 * sc + bv.x;
        w.y = a1 * sc + bv.y;
        w.z = a2 * sc + bv.z;
        w.w = a3 * sc + bv.w;
        ((float4*)(out + (size_t)v * C))[ch] = w;
    }
}

extern "C" void kernel_launch(void* const* d_in, const int* in_sizes, int n_in,
                              void* d_out, int out_size, void* d_ws, size_t ws_size,
                              hipStream_t stream) {
    const float* x = (const float*)d_in[0];     // [N_NODES,128] f32
    const int* node_idx = (const int*)d_in[1];  // [2, NNZ] row-major int32
    const int nnz = in_sizes[1] / 2;
    const int* edge_idx = node_idx + nnz;
    const float* W = (const float*)d_in[2];     // [128,128] f32
    const float* bias = (const float*)d_in[3];  // [128] f32
    float* out = (float*)d_out;                 // [N_NODES,128] f32

    int nb1 = (nnz + BCHUNK - 1) / BCHUNK;      // 245 hist/place blocks
    int scanN = NBUCKC * nb1;                   // 287140 count-matrix entries
    int scanBlocks = (scanN + 1023) / 1024;     // 281 (<= 512 for scan_b2)

    // workspace layout (~20.3 MB), all 16B-aligned:
    u16* Wt = (u16*)d_ws;                           // 32 KB
    u16* ef = Wt + 16384;                           // 12.8 MB
    u32* cntM = (u32*)(ef + (size_t)N_EDGES * C);   // scanN u32 (1.15 MB)
    u32* offM = cntM + scanN;                       // scanN u32 (1.15 MB)
    u32* bsum2 = offM + scanN;                      // 512 u32
    uint2* rowinfo = (uint2*)(bsum2 + 512);         // 150000 uint2 (1.2 MB)
    u32* csrC = (u32*)(rowinfo + NCNT);             // 2*nnz u32 (4 MB)

    // d_out (51.2 MB f32) doubles as scratch:
    //   [0, 25.6 MB):    xw bf16        — consumed by edge_gather
    //   [25.6, 29.6 MB): stage (packed) — consumed by bucket_csr_k
    // node_gather then overwrites the whole buffer with the f32 output.
    u16* xw = (u16*)d_out;
    u32* stage = (u32*)((char*)d_out + (size_t)N_NODES * C * 2);

    prep_k<<<64 + nb1, 256, 0, stream>>>(W, Wt, node_idx, edge_idx, cntM, nnz, nb1);
    gemm_k<<<GEMM_BLOCKS, 256, 0, stream>>>(x, Wt, xw);
    scan_a2<<<scanBlocks, 256, 0, stream>>>(cntM, offM, bsum2, scanN);
    scan_b2<<<1, 256, 0, stream>>>(bsum2, scanBlocks);
    bucket_place_k<<<nb1, 256, 0, stream>>>(node_idx, edge_idx, offM, bsum2,
                                            stage, nnz, nb1);
    bucket_csr_k<<<NBUCKC, 256, 0, stream>>>(offM, bsum2, stage, csrC, rowinfo,
                                             nnz, nb1);
    // 1 edge/node per wave, 4 waves per block
    edge_gather_k<<<(N_EDGES + 3) / 4, 256, 0, stream>>>(xw, rowinfo, csrC, ef);
    node_gather_k<<<(N_NODES + 3) / 4, 256, 0, stream>>>(ef, rowinfo, csrC, bias, out);
}

// Round 12
// 208.471 us; speedup vs baseline: 1.0294x; 1.0294x over previous
//
#include <hip/hip_runtime.h>

typedef unsigned short u16;
typedef unsigned int u32;

#define N_NODES 100000
#define N_EDGES 50000
#define C 128
#define NCNT (N_EDGES + N_NODES)  // 150000 combined key space (edges then nodes)
#define NBUCKC 1172               // ceil(150000 / 128) coarse buckets (key>>7)
#define BCHUNK 2048               // incidences per bucketize block

static __device__ __forceinline__ float bf2f(u16 h) {
    u32 u = ((u32)h) << 16;
    float f;
    __builtin_memcpy(&f, &u, 4);
    return f;
}

static __device__ __forceinline__ u16 f2bf(float f) {
    u32 u;
    __builtin_memcpy(&u, &f, 4);
    return (u16)((u + 0x7fffu + ((u >> 16) & 1u)) >> 16);  // RNE
}

typedef short s16x8 __attribute__((ext_vector_type(8)));
typedef float f32x4 __attribute__((ext_vector_type(4)));

// ---------------- prep: W transpose (blocks 0-63) + bucket hist (64..) -----
__global__ __launch_bounds__(256) void prep_k(
    const float* __restrict__ W, u16* __restrict__ Wt,
    const int* __restrict__ ni, const int* __restrict__ ei,
    u32* __restrict__ cntM, int nnz, int nb1) {
    __shared__ u32 h[NBUCKC];
    if (blockIdx.x < 64) {
        int idx = blockIdx.x * 256 + threadIdx.x;  // 16384 total
        int k = idx >> 7, oc = idx & 127;
        Wt[oc * 128 + k] = f2bf(W[k * 128 + oc]);
        return;
    }
    int blk = blockIdx.x - 64;
    for (int b = threadIdx.x; b < NBUCKC; b += 256) h[b] = 0;
    __syncthreads();
    int i0 = blk * BCHUNK;
    int iend = min(i0 + BCHUNK, nnz);
    for (int i = i0 + threadIdx.x; i < iend; i += 256) {
        int e = ei[i], n = ni[i];
        atomicAdd(&h[e >> 7], 1u);                 // LDS atomic (fast)
        atomicAdd(&h[(N_EDGES + n) >> 7], 1u);
    }
    __syncthreads();
    for (int b = threadIdx.x; b < NBUCKC; b += 256)
        cntM[(size_t)b * nb1 + blk] = h[b];        // plain stores
}

// ---------------- scan A: generic exclusive scan ---------------------------
__global__ __launch_bounds__(256) void scan_a2(const u32* __restrict__ cnt,
                                               u32* __restrict__ off,
                                               u32* __restrict__ bsum, int N) {
    __shared__ u32 wsum[4];
    int tid = threadIdx.x;
    int base = blockIdx.x * 1024 + tid * 4;
    u32 v0 = 0, v1 = 0, v2 = 0, v3 = 0;
    if (base + 3 < N) {
        uint4 v = *(const uint4*)(cnt + base);
        v0 = v.x; v1 = v.y; v2 = v.z; v3 = v.w;
    } else {
        if (base + 0 < N) v0 = cnt[base + 0];
        if (base + 1 < N) v1 = cnt[base + 1];
        if (base + 2 < N) v2 = cnt[base + 2];
        if (base + 3 < N) v3 = cnt[base + 3];
    }
    u32 s = v0 + v1 + v2 + v3;
    int lane = tid & 63, wv = tid >> 6;
    u32 x = s;
    for (int d = 1; d < 64; d <<= 1) {
        u32 y = __shfl_up(x, (unsigned)d);
        if (lane >= d) x += y;
    }
    if (lane == 63) wsum[wv] = x;
    __syncthreads();
    u32 wo = 0;
    for (int w = 0; w < 4; ++w) wo += (w < wv) ? wsum[w] : 0u;
    u32 ex = wo + x - s;
    if (base + 0 < N) off[base + 0] = ex;
    if (base + 1 < N) off[base + 1] = ex + v0;
    if (base + 2 < N) off[base + 2] = ex + v0 + v1;
    if (base + 3 < N) off[base + 3] = ex + v0 + v1 + v2;
    if (tid == 255) bsum[blockIdx.x] = wo + x;  // block total
}

// ---------------- scan B: exclusive scan of up to 512 block sums ----------
__global__ __launch_bounds__(256) void scan_b2(u32* __restrict__ bsum, int nb) {
    __shared__ u32 wsum[4];
    int t = threadIdx.x;
    u32 v0 = (2 * t < nb) ? bsum[2 * t] : 0u;
    u32 v1 = (2 * t + 1 < nb) ? bsum[2 * t + 1] : 0u;
    u32 s = v0 + v1;
    int lane = t & 63, wv = t >> 6;
    u32 x = s;
    for (int d = 1; d < 64; d <<= 1) {
        u32 y = __shfl_up(x, (unsigned)d);
        if (lane >= d) x += y;
    }
    if (lane == 63) wsum[wv] = x;
    __syncthreads();
    u32 wo = 0;
    for (int w = 0; w < 4; ++w) wo += (w < wv) ? wsum[w] : 0u;
    u32 ex = wo + x - s;
    if (2 * t < nb) bsum[2 * t] = ex;
    if (2 * t + 1 < nb) bsum[2 * t + 1] = ex + v0;
}

// ---------------- place entries bucket-grouped (LDS cursors only) ----------
__global__ __launch_bounds__(256) void bucket_place_k(
    const int* __restrict__ ni, const int* __restrict__ ei,
    const u32* __restrict__ offM, const u32* __restrict__ bsum,
    u32* __restrict__ stage, int nnz, int nb1) {
    __shared__ u32 cur[NBUCKC];
    for (int b = threadIdx.x; b < NBUCKC; b += 256) {
        size_t idx = (size_t)b * nb1 + blockIdx.x;
        cur[b] = offM[idx] + bsum[idx >> 10];
    }
    __syncthreads();
    int i0 = blockIdx.x * BCHUNK;
    int iend = min(i0 + BCHUNK, nnz);
    for (int i = i0 + threadIdx.x; i < iend; i += 256) {
        int e = ei[i], n = ni[i];
        u32 p1 = atomicAdd(&cur[e >> 7], 1u);
        stage[p1] = ((u32)(e & 127) << 17) | (u32)n;
        int k2 = N_EDGES + n;
        u32 p2 = atomicAdd(&cur[k2 >> 7], 1u);
        stage[p2] = ((u32)(k2 & 127) << 17) | (u32)e;
    }
}

// ---------------- per-bucket fine counting-sort -> dense CSR + rowinfo -----
__global__ __launch_bounds__(256) void bucket_csr_k(
    const u32* __restrict__ offM, const u32* __restrict__ bsum,
    const u32* __restrict__ stage, u32* __restrict__ csr,
    uint2* __restrict__ rowinfo, int nnz, int nb1) {
    __shared__ u32 h[128];
    __shared__ u32 ks[128];
    int b = blockIdx.x;
    size_t i0 = (size_t)b * nb1;
    u32 gstart = offM[i0] + bsum[i0 >> 10];
    u32 gend;
    if (b + 1 < NBUCKC) {
        size_t i1 = (size_t)(b + 1) * nb1;
        gend = offM[i1] + bsum[i1 >> 10];
    } else {
        gend = (u32)(2 * nnz);
    }
    int size = (int)(gend - gstart);
    if (threadIdx.x < 128) h[threadIdx.x] = 0;
    __syncthreads();
    for (int i = threadIdx.x; i < size; i += 256)
        atomicAdd(&h[stage[gstart + i] >> 17], 1u);
    __syncthreads();
    if (threadIdx.x < 64) {
        int l = threadIdx.x;
        u32 s0 = h[2 * l], s1 = h[2 * l + 1];
        u32 ps = s0 + s1;
        u32 x = ps;
        for (int d = 1; d < 64; d <<= 1) {
            u32 y = __shfl_up(x, (unsigned)d);
            if (l >= d) x += y;
        }
        u32 ex = x - ps;  // exclusive pair prefix within bucket
        ks[2 * l] = ex;
        ks[2 * l + 1] = ex + s0;
        int gk = b * 128 + 2 * l;
        if (gk < NCNT) rowinfo[gk] = make_uint2(gstart + ex, s0);
        if (gk + 1 < NCNT) rowinfo[gk + 1] = make_uint2(gstart + ex + s0, s1);
    }
    __syncthreads();
    for (int i = threadIdx.x; i < size; i += 256) {
        u32 en = stage[gstart + i];
        u32 kl = en >> 17;
        u32 p = atomicAdd(&ks[kl], 1u);
        csr[gstart + p] = en & 0x1FFFFu;
    }
}

// ---------------- edge gather on RAW x (r12 restructure) -------------------
// Operator commute: out = D^-1 H B^-1 H^T (XW) = D^-1 H (B^-1 H^T X) W.
// G[e] = bf16(B^-1_e * sum x[nodes of e]) gathered from f32 x directly;
// the GEMM then runs on 50K bf16 rows instead of 100K f32 rows (1/4 the
// traffic, 1/2 the tiles) and the 25.6MB xw round-trip disappears.
// Pair-row: lanes 0-31 row of entry t+2k, lanes 32-63 row t+2k+1, float4
// per lane (16B x 32 lanes = full 512B f32 row); shfl_xor(32) merges.
__global__ __launch_bounds__(256) void edge_gather_x(const float* __restrict__ x,
                                                     const uint2* __restrict__ rowinfo,
                                                     const u32* __restrict__ csrC,
                                                     u16* __restrict__ G) {
    int e = blockIdx.x * 4 + (threadIdx.x >> 6);
    if (e >= N_EDGES) return;
    int lane = threadIdx.x & 63;
    int half = lane >> 5, ch = lane & 31;
    uint2 ri = rowinfo[e];
    u32 deg = ri.y;
    u32 start = ri.x;  // absolute position in combined csr
    float a0 = 0.f, a1 = 0.f, a2 = 0.f, a3 = 0.f;
    for (u32 base = 0; base < deg; base += 64) {
        int m = (int)min(64u, deg - base);
        int myidx = (lane < m) ? (int)csrC[start + base + lane] : 0;
        for (int t = 0; t < m; t += 8) {
            int e0 = min(t + 0 + half, m - 1), e1 = min(t + 2 + half, m - 1);
            int e2 = min(t + 4 + half, m - 1), e3 = min(t + 6 + half, m - 1);
            int r0 = __shfl(myidx, e0), r1 = __shfl(myidx, e1);
            int r2 = __shfl(myidx, e2), r3 = __shfl(myidx, e3);
            float4 v0 = ((const float4*)(x + (size_t)r0 * C))[ch];
            float4 v1 = ((const float4*)(x + (size_t)r1 * C))[ch];
            float4 v2 = ((const float4*)(x + (size_t)r2 * C))[ch];
            float4 v3 = ((const float4*)(x + (size_t)r3 * C))[ch];
            float m0 = (t + 0 + half < m) ? 1.f : 0.f;
            float m1 = (t + 2 + half < m) ? 1.f : 0.f;
            float m2 = (t + 4 + half < m) ? 1.f : 0.f;
            float m3 = (t + 6 + half < m) ? 1.f : 0.f;
            a0 += m0 * v0.x + m1 * v1.x + m2 * v2.x + m3 * v3.x;
            a1 += m0 * v0.y + m1 * v1.y + m2 * v2.y + m3 * v3.y;
            a2 += m0 * v0.z + m1 * v1.z + m2 * v2.z + m3 * v3.z;
            a3 += m0 * v0.w + m1 * v1.w + m2 * v2.w + m3 * v3.w;
        }
    }
    a0 += __shfl_xor(a0, 32);
    a1 += __shfl_xor(a1, 32);
    a2 += __shfl_xor(a2, 32);
    a3 += __shfl_xor(a3, 32);
    float sc = deg ? 1.f / (float)deg : 0.f;
    if (lane < 32) {
        uint2 w;
        w.x = (u32)f2bf(a0 * sc) | ((u32)f2bf(a1 * sc) << 16);
        w.y = (u32)f2bf(a2 * sc) | ((u32)f2bf(a3 * sc) << 16);
        ((uint2*)(G + (size_t)e * C))[ch] = w;
    }
}

// ---------------- GEMM on edge features: ef = G @ W (bf16 in, bf16 out) ----
// 50000 rows, 3125 tiles, 782 blocks. bf16 A rows load directly as s16x8
// (16B/lane, no f32->bf16 convert). Simple structure — 7 pipelining/staging
// variants proved null; per-pass cost scales with traffic (26MB -> ~15-20us).
// A[m=lane&15][k=quad*8+j]; D col=lane&15, row=quad*4+reg (verified m89/m91).
__global__ __launch_bounds__(256) void gemm_e(
    const u16* __restrict__ G, const u16* __restrict__ Wt,
    u16* __restrict__ ef) {
    int wave = threadIdx.x >> 6;
    int tile = blockIdx.x * 4 + wave;
    if (tile >= 3125) return;
    int lane = threadIdx.x & 63;
    int m = lane & 15;
    int quad = lane >> 4;
    int row0 = tile * 16;

    const u16* gr = G + (size_t)(row0 + m) * C + quad * 8;
    union { uint4 u; s16x8 v; } a[4];
#pragma unroll
    for (int kk = 0; kk < 4; ++kk)
        a[kk].u = *(const uint4*)(gr + kk * 32);

    f32x4 acc[8];
#pragma unroll
    for (int nt = 0; nt < 8; ++nt) acc[nt] = (f32x4){0.f, 0.f, 0.f, 0.f};

#pragma unroll
    for (int kk = 0; kk < 4; ++kk) {
        int kb = kk * 32 + quad * 8;
#pragma unroll
        for (int nt = 0; nt < 8; ++nt) {
            union { uint4 u; s16x8 v; } b;
            b.u = *(const uint4*)(Wt + (size_t)(nt * 16 + m) * C + kb);
            acc[nt] = __builtin_amdgcn_mfma_f32_16x16x32_bf16(a[kk].v, b.v, acc[nt], 0, 0, 0);
        }
    }

#pragma unroll
    for (int nt = 0; nt < 8; ++nt) {
#pragma unroll
        for (int r = 0; r < 4; ++r) {
            int row = row0 + quad * 4 + r;
            ef[(size_t)row * C + nt * 16 + m] = f2bf(acc[nt][r]);
        }
    }
}

// ---------------- node gather over CSR: 1 node per wave (r10 pair-row) -----
// out[v] = f32( D^-1_v * sum ef[edges of v] + b )
__global__ __launch_bounds__(256) void node_gather_k(const u16* __restrict__ ef,
                                                     const uint2* __restrict__ rowinfo,
                                                     const u32* __restrict__ csrC,
                                                     const float* __restrict__ bias,
                                                     float* __restrict__ out) {
    int v = blockIdx.x * 4 + (threadIdx.x >> 6);
    if (v >= N_NODES) return;
    int lane = threadIdx.x & 63;
    int half = lane >> 5, ch = lane & 31;
    uint2 ri = rowinfo[N_EDGES + v];
    u32 deg = ri.y;
    u32 start = ri.x;
    float a0 = 0.f, a1 = 0.f, a2 = 0.f, a3 = 0.f;
    for (u32 base = 0; base < deg; base += 64) {
        int m = (int)min(64u, deg - base);
        int myidx = (lane < m) ? (int)csrC[start + base + lane] : 0;
        for (int t = 0; t < m; t += 8) {
            int e0 = min(t + 0 + half, m - 1), e1 = min(t + 2 + half, m - 1);
            int e2 = min(t + 4 + half, m - 1), e3 = min(t + 6 + half, m - 1);
            int r0 = __shfl(myidx, e0), r1 = __shfl(myidx, e1);
            int r2 = __shfl(myidx, e2), r3 = __shfl(myidx, e3);
            uint2 u0 = ((const uint2*)(ef + (size_t)r0 * C))[ch];
            uint2 u1 = ((const uint2*)(ef + (size_t)r1 * C))[ch];
            uint2 u2 = ((const uint2*)(ef + (size_t)r2 * C))[ch];
            uint2 u3 = ((const uint2*)(ef + (size_t)r3 * C))[ch];
            float m0 = (t + 0 + half < m) ? 1.f : 0.f;
            float m1 = (t + 2 + half < m) ? 1.f : 0.f;
            float m2 = (t + 4 + half < m) ? 1.f : 0.f;
            float m3 = (t + 6 + half < m) ? 1.f : 0.f;
            a0 += m0 * bf2f((u16)(u0.x & 0xffffu)) + m1 * bf2f((u16)(u1.x & 0xffffu))
                + m2 * bf2f((u16)(u2.x & 0xffffu)) + m3 * bf2f((u16)(u3.x & 0xffffu));
            a1 += m0 * bf2f((u16)(u0.x >> 16)) + m1 * bf2f((u16)(u1.x >> 16))
                + m2 * bf2f((u16)(u2.x >> 16)) + m3 * bf2f((u16)(u3.x >> 16));
            a2 += m0 * bf2f((u16)(u0.y & 0xffffu)) + m1 * bf2f((u16)(u1.y & 0xffffu))
                + m2 * bf2f((u16)(u2.y & 0xffffu)) + m3 * bf2f((u16)(u3.y & 0xffffu));
            a3 += m0 * bf2f((u16)(u0.y >> 16)) + m1 * bf2f((u16)(u1.y >> 16))
                + m2 * bf2f((u16)(u2.y >> 16)) + m3 * bf2f((u16)(u3.y >> 16));
        }
    }
    a0 += __shfl_xor(a0, 32);
    a1 += __shfl_xor(a1, 32);
    a2 += __shfl_xor(a2, 32);
    a3 += __shfl_xor(a3, 32);
    float sc = deg ? 1.f / (float)deg : 0.f;
    if (lane < 32) {
        float4 bv = *(const float4*)(bias + ch * 4);
        float4 w;
        w.x = a0 * sc + bv.x;
        w.y = a1 * sc + bv.y;
        w.z = a2 * sc + bv.z;
        w.w = a3 * sc + bv.w;
        ((float4*)(out + (size_t)v * C))[ch] = w;
    }
}

extern "C" void kernel_launch(void* const* d_in, const int* in_sizes, int n_in,
                              void* d_out, int out_size, void* d_ws, size_t ws_size,
                              hipStream_t stream) {
    const float* x = (const float*)d_in[0];     // [N_NODES,128] f32
    const int* node_idx = (const int*)d_in[1];  // [2, NNZ] row-major int32
    const int nnz = in_sizes[1] / 2;
    const int* edge_idx = node_idx + nnz;
    const float* W = (const float*)d_in[2];     // [128,128] f32
    const float* bias = (const float*)d_in[3];  // [128] f32
    float* out = (float*)d_out;                 // [N_NODES,128] f32

    int nb1 = (nnz + BCHUNK - 1) / BCHUNK;      // 245 hist/place blocks
    int scanN = NBUCKC * nb1;                   // 287140 count-matrix entries
    int scanBlocks = (scanN + 1023) / 1024;     // 281 (<= 512 for scan_b2)

    // workspace layout (~20.3 MB), all 16B-aligned:
    u16* Wt = (u16*)d_ws;                           // 32 KB
    u16* ef = Wt + 16384;                           // 12.8 MB
    u32* cntM = (u32*)(ef + (size_t)N_EDGES * C);   // scanN u32 (1.15 MB)
    u32* offM = cntM + scanN;                       // scanN u32 (1.15 MB)
    u32* bsum2 = offM + scanN;                      // 512 u32
    uint2* rowinfo = (uint2*)(bsum2 + 512);         // 150000 uint2 (1.2 MB)
    u32* csrC = (u32*)(rowinfo + NCNT);             // 2*nnz u32 (4 MB)

    // d_out (51.2 MB f32) doubles as scratch:
    //   [0, 12.8 MB):    G bf16         — written by edge_gather_x, read gemm_e
    //   [25.6, 29.6 MB): stage (packed) — written place, consumed bucket_csr
    // node_gather then overwrites the whole buffer with the f32 output.
    u16* G = (u16*)d_out;
    u32* stage = (u32*)((char*)d_out + (size_t)N_NODES * C * 2);

    prep_k<<<64 + nb1, 256, 0, stream>>>(W, Wt, node_idx, edge_idx, cntM, nnz, nb1);
    scan_a2<<<scanBlocks, 256, 0, stream>>>(cntM, offM, bsum2, scanN);
    scan_b2<<<1, 256, 0, stream>>>(bsum2, scanBlocks);
    bucket_place_k<<<nb1, 256, 0, stream>>>(node_idx, edge_idx, offM, bsum2,
                                            stage, nnz, nb1);
    bucket_csr_k<<<NBUCKC, 256, 0, stream>>>(offM, bsum2, stage, csrC, rowinfo,
                                             nnz, nb1);
    // gather raw x rows -> G (B^-1 applied); then small bf16 GEMM; then nodes
    edge_gather_x<<<(N_EDGES + 3) / 4, 256, 0, stream>>>(x, rowinfo, csrC, G);
    gemm_e<<<(3125 + 3) / 4, 256, 0, stream>>>(G, Wt, ef);
    node_gather_k<<<(N_NODES + 3) / 4, 256, 0, stream>>>(ef, rowinfo, csrC, bias, out);
}

// Round 13
// 197.331 us; speedup vs baseline: 1.0876x; 1.0565x over previous
//
#include <hip/hip_runtime.h>

typedef unsigned short u16;
typedef unsigned int u32;

#define N_NODES 100000
#define N_EDGES 50000
#define C 128
#define NCNT (N_EDGES + N_NODES)  // 150000 combined key space (edges then nodes)
#define NBUCKC 1172               // ceil(150000 / 128) coarse buckets (key>>7)
#define BCHUNK 2048               // incidences per bucketize block
#define GSTRIDE 136               // LDS G-tile row stride in u16 (272B: pads
                                  // b128 A-reads to the 8-words/bank floor)

static __device__ __forceinline__ float bf2f(u16 h) {
    u32 u = ((u32)h) << 16;
    float f;
    __builtin_memcpy(&f, &u, 4);
    return f;
}

static __device__ __forceinline__ u16 f2bf(float f) {
    u32 u;
    __builtin_memcpy(&u, &f, 4);
    return (u16)((u + 0x7fffu + ((u >> 16) & 1u)) >> 16);  // RNE
}

typedef short s16x8 __attribute__((ext_vector_type(8)));
typedef float f32x4 __attribute__((ext_vector_type(4)));

// ---------------- prep: W transpose (blocks 0-63) + bucket hist (64..) -----
__global__ __launch_bounds__(256) void prep_k(
    const float* __restrict__ W, u16* __restrict__ Wt,
    const int* __restrict__ ni, const int* __restrict__ ei,
    u32* __restrict__ cntM, int nnz, int nb1) {
    __shared__ u32 h[NBUCKC];
    if (blockIdx.x < 64) {
        int idx = blockIdx.x * 256 + threadIdx.x;  // 16384 total
        int k = idx >> 7, oc = idx & 127;
        Wt[oc * 128 + k] = f2bf(W[k * 128 + oc]);
        return;
    }
    int blk = blockIdx.x - 64;
    for (int b = threadIdx.x; b < NBUCKC; b += 256) h[b] = 0;
    __syncthreads();
    int i0 = blk * BCHUNK;
    int iend = min(i0 + BCHUNK, nnz);
    for (int i = i0 + threadIdx.x; i < iend; i += 256) {
        int e = ei[i], n = ni[i];
        atomicAdd(&h[e >> 7], 1u);                 // LDS atomic (fast)
        atomicAdd(&h[(N_EDGES + n) >> 7], 1u);
    }
    __syncthreads();
    for (int b = threadIdx.x; b < NBUCKC; b += 256)
        cntM[(size_t)b * nb1 + blk] = h[b];        // plain stores
}

// ---------------- scan A: generic exclusive scan ---------------------------
__global__ __launch_bounds__(256) void scan_a2(const u32* __restrict__ cnt,
                                               u32* __restrict__ off,
                                               u32* __restrict__ bsum, int N) {
    __shared__ u32 wsum[4];
    int tid = threadIdx.x;
    int base = blockIdx.x * 1024 + tid * 4;
    u32 v0 = 0, v1 = 0, v2 = 0, v3 = 0;
    if (base + 3 < N) {
        uint4 v = *(const uint4*)(cnt + base);
        v0 = v.x; v1 = v.y; v2 = v.z; v3 = v.w;
    } else {
        if (base + 0 < N) v0 = cnt[base + 0];
        if (base + 1 < N) v1 = cnt[base + 1];
        if (base + 2 < N) v2 = cnt[base + 2];
        if (base + 3 < N) v3 = cnt[base + 3];
    }
    u32 s = v0 + v1 + v2 + v3;
    int lane = tid & 63, wv = tid >> 6;
    u32 x = s;
    for (int d = 1; d < 64; d <<= 1) {
        u32 y = __shfl_up(x, (unsigned)d);
        if (lane >= d) x += y;
    }
    if (lane == 63) wsum[wv] = x;
    __syncthreads();
    u32 wo = 0;
    for (int w = 0; w < 4; ++w) wo += (w < wv) ? wsum[w] : 0u;
    u32 ex = wo + x - s;
    if (base + 0 < N) off[base + 0] = ex;
    if (base + 1 < N) off[base + 1] = ex + v0;
    if (base + 2 < N) off[base + 2] = ex + v0 + v1;
    if (base + 3 < N) off[base + 3] = ex + v0 + v1 + v2;
    if (tid == 255) bsum[blockIdx.x] = wo + x;  // block total
}

// ---------------- scan B: exclusive scan of up to 512 block sums ----------
__global__ __launch_bounds__(256) void scan_b2(u32* __restrict__ bsum, int nb) {
    __shared__ u32 wsum[4];
    int t = threadIdx.x;
    u32 v0 = (2 * t < nb) ? bsum[2 * t] : 0u;
    u32 v1 = (2 * t + 1 < nb) ? bsum[2 * t + 1] : 0u;
    u32 s = v0 + v1;
    int lane = t & 63, wv = t >> 6;
    u32 x = s;
    for (int d = 1; d < 64; d <<= 1) {
        u32 y = __shfl_up(x, (unsigned)d);
        if (lane >= d) x += y;
    }
    if (lane == 63) wsum[wv] = x;
    __syncthreads();
    u32 wo = 0;
    for (int w = 0; w < 4; ++w) wo += (w < wv) ? wsum[w] : 0u;
    u32 ex = wo + x - s;
    if (2 * t < nb) bsum[2 * t] = ex;
    if (2 * t + 1 < nb) bsum[2 * t + 1] = ex + v0;
}

// ---------------- place entries bucket-grouped (LDS cursors only) ----------
__global__ __launch_bounds__(256) void bucket_place_k(
    const int* __restrict__ ni, const int* __restrict__ ei,
    const u32* __restrict__ offM, const u32* __restrict__ bsum,
    u32* __restrict__ stage, int nnz, int nb1) {
    __shared__ u32 cur[NBUCKC];
    for (int b = threadIdx.x; b < NBUCKC; b += 256) {
        size_t idx = (size_t)b * nb1 + blockIdx.x;
        cur[b] = offM[idx] + bsum[idx >> 10];
    }
    __syncthreads();
    int i0 = blockIdx.x * BCHUNK;
    int iend = min(i0 + BCHUNK, nnz);
    for (int i = i0 + threadIdx.x; i < iend; i += 256) {
        int e = ei[i], n = ni[i];
        u32 p1 = atomicAdd(&cur[e >> 7], 1u);
        stage[p1] = ((u32)(e & 127) << 17) | (u32)n;
        int k2 = N_EDGES + n;
        u32 p2 = atomicAdd(&cur[k2 >> 7], 1u);
        stage[p2] = ((u32)(k2 & 127) << 17) | (u32)e;
    }
}

// ---------------- per-bucket fine counting-sort -> dense CSR + rowinfo -----
__global__ __launch_bounds__(256) void bucket_csr_k(
    const u32* __restrict__ offM, const u32* __restrict__ bsum,
    const u32* __restrict__ stage, u32* __restrict__ csr,
    uint2* __restrict__ rowinfo, int nnz, int nb1) {
    __shared__ u32 h[128];
    __shared__ u32 ks[128];
    int b = blockIdx.x;
    size_t i0 = (size_t)b * nb1;
    u32 gstart = offM[i0] + bsum[i0 >> 10];
    u32 gend;
    if (b + 1 < NBUCKC) {
        size_t i1 = (size_t)(b + 1) * nb1;
        gend = offM[i1] + bsum[i1 >> 10];
    } else {
        gend = (u32)(2 * nnz);
    }
    int size = (int)(gend - gstart);
    if (threadIdx.x < 128) h[threadIdx.x] = 0;
    __syncthreads();
    for (int i = threadIdx.x; i < size; i += 256)
        atomicAdd(&h[stage[gstart + i] >> 17], 1u);
    __syncthreads();
    if (threadIdx.x < 64) {
        int l = threadIdx.x;
        u32 s0 = h[2 * l], s1 = h[2 * l + 1];
        u32 ps = s0 + s1;
        u32 x = ps;
        for (int d = 1; d < 64; d <<= 1) {
            u32 y = __shfl_up(x, (unsigned)d);
            if (l >= d) x += y;
        }
        u32 ex = x - ps;  // exclusive pair prefix within bucket
        ks[2 * l] = ex;
        ks[2 * l + 1] = ex + s0;
        int gk = b * 128 + 2 * l;
        if (gk < NCNT) rowinfo[gk] = make_uint2(gstart + ex, s0);
        if (gk + 1 < NCNT) rowinfo[gk + 1] = make_uint2(gstart + ex + s0, s1);
    }
    __syncthreads();
    for (int i = threadIdx.x; i < size; i += 256) {
        u32 en = stage[gstart + i];
        u32 kl = en >> 17;
        u32 p = atomicAdd(&ks[kl], 1u);
        csr[gstart + p] = en & 0x1FFFFu;
    }
}

// ---------------- FUSED edge gather + GEMM (r13) ---------------------------
// Block of 4 waves owns 16 edges == one MFMA row-tile (50000 = 3125*16).
// Each wave pair-row-gathers 4 edges from raw f32 x (commuted form:
// G[e] = B^-1_e sum x[nodes of e]), writes bf16 rows to a 4.4KB LDS tile
// (row stride 272B -> b128 A-reads hit the 8-words/bank floor), syncs, then
// computes 2 of the 8 nt-column-tiles: ef[16 edges][128] = G_tile @ W.
// Kills the separate gemm_e dispatch + the 25.6MB G round-trip.
// A[m=lane&15][k=quad*8+j]; D col=lane&15, row=quad*4+reg (verified m89/m91).
__global__ __launch_bounds__(256) void edge_gemm_k(
    const float* __restrict__ x, const uint2* __restrict__ rowinfo,
    const u32* __restrict__ csrC, const u16* __restrict__ Wt,
    u16* __restrict__ ef) {
    __shared__ __align__(16) u16 gs[16 * GSTRIDE];  // 4352 B
    int lane = threadIdx.x & 63;
    int wave = threadIdx.x >> 6;
    int half = lane >> 5, ch = lane & 31;
    int ebase = blockIdx.x * 16;

    // gather 4 edges per wave: tile rows wave, wave+4, wave+8, wave+12
#pragma unroll
    for (int s = 0; s < 4; ++s) {
        int row = wave + s * 4;
        int e = ebase + row;
        uint2 ri = rowinfo[e];
        u32 deg = ri.y;
        u32 start = ri.x;
        float a0 = 0.f, a1 = 0.f, a2 = 0.f, a3 = 0.f;
        for (u32 base = 0; base < deg; base += 64) {
            int m = (int)min(64u, deg - base);
            int myidx = (lane < m) ? (int)csrC[start + base + lane] : 0;
            for (int t = 0; t < m; t += 8) {
                int e0 = min(t + 0 + half, m - 1), e1 = min(t + 2 + half, m - 1);
                int e2 = min(t + 4 + half, m - 1), e3 = min(t + 6 + half, m - 1);
                int r0 = __shfl(myidx, e0), r1 = __shfl(myidx, e1);
                int r2 = __shfl(myidx, e2), r3 = __shfl(myidx, e3);
                float4 v0 = ((const float4*)(x + (size_t)r0 * C))[ch];
                float4 v1 = ((const float4*)(x + (size_t)r1 * C))[ch];
                float4 v2 = ((const float4*)(x + (size_t)r2 * C))[ch];
                float4 v3 = ((const float4*)(x + (size_t)r3 * C))[ch];
                float m0 = (t + 0 + half < m) ? 1.f : 0.f;
                float m1 = (t + 2 + half < m) ? 1.f : 0.f;
                float m2 = (t + 4 + half < m) ? 1.f : 0.f;
                float m3 = (t + 6 + half < m) ? 1.f : 0.f;
                a0 += m0 * v0.x + m1 * v1.x + m2 * v2.x + m3 * v3.x;
                a1 += m0 * v0.y + m1 * v1.y + m2 * v2.y + m3 * v3.y;
                a2 += m0 * v0.z + m1 * v1.z + m2 * v2.z + m3 * v3.z;
                a3 += m0 * v0.w + m1 * v1.w + m2 * v2.w + m3 * v3.w;
            }
        }
        a0 += __shfl_xor(a0, 32);
        a1 += __shfl_xor(a1, 32);
        a2 += __shfl_xor(a2, 32);
        a3 += __shfl_xor(a3, 32);
        float sc = deg ? 1.f / (float)deg : 0.f;
        if (lane < 32) {
            uint2 w;
            w.x = (u32)f2bf(a0 * sc) | ((u32)f2bf(a1 * sc) << 16);
            w.y = (u32)f2bf(a2 * sc) | ((u32)f2bf(a3 * sc) << 16);
            *(uint2*)(&gs[row * GSTRIDE + ch * 4]) = w;  // 8B, 8B-aligned
        }
    }
    __syncthreads();

    // MFMA: wave computes nt = 2*wave, 2*wave+1 over the 16-row LDS tile
    int m = lane & 15;
    int quad = lane >> 4;
    union { uint4 u; s16x8 v; } a[4];
#pragma unroll
    for (int kk = 0; kk < 4; ++kk)
        a[kk].u = *(const uint4*)(&gs[m * GSTRIDE + quad * 8 + kk * 32]);

    f32x4 acc[2];
    acc[0] = (f32x4){0.f, 0.f, 0.f, 0.f};
    acc[1] = (f32x4){0.f, 0.f, 0.f, 0.f};
#pragma unroll
    for (int kk = 0; kk < 4; ++kk) {
        int kb = kk * 32 + quad * 8;
#pragma unroll
        for (int j = 0; j < 2; ++j) {
            int nt = wave * 2 + j;
            union { uint4 u; s16x8 v; } b;
            b.u = *(const uint4*)(Wt + (size_t)(nt * 16 + m) * C + kb);
            acc[j] = __builtin_amdgcn_mfma_f32_16x16x32_bf16(a[kk].v, b.v, acc[j], 0, 0, 0);
        }
    }
#pragma unroll
    for (int j = 0; j < 2; ++j) {
        int nt = wave * 2 + j;
#pragma unroll
        for (int r = 0; r < 4; ++r)
            ef[(size_t)(ebase + quad * 4 + r) * C + nt * 16 + m] = f2bf(acc[j][r]);
    }
}

// ---------------- node gather over CSR: 1 node per wave (r10 pair-row) -----
// out[v] = f32( D^-1_v * sum ef[edges of v] + b )
__global__ __launch_bounds__(256) void node_gather_k(const u16* __restrict__ ef,
                                                     const uint2* __restrict__ rowinfo,
                                                     const u32* __restrict__ csrC,
                                                     const float* __restrict__ bias,
                                                     float* __restrict__ out) {
    int v = blockIdx.x * 4 + (threadIdx.x >> 6);
    if (v >= N_NODES) return;
    int lane = threadIdx.x & 63;
    int half = lane >> 5, ch = lane & 31;
    uint2 ri = rowinfo[N_EDGES + v];
    u32 deg = ri.y;
    u32 start = ri.x;
    float a0 = 0.f, a1 = 0.f, a2 = 0.f, a3 = 0.f;
    for (u32 base = 0; base < deg; base += 64) {
        int m = (int)min(64u, deg - base);
        int myidx = (lane < m) ? (int)csrC[start + base + lane] : 0;
        for (int t = 0; t < m; t += 8) {
            int e0 = min(t + 0 + half, m - 1), e1 = min(t + 2 + half, m - 1);
            int e2 = min(t + 4 + half, m - 1), e3 = min(t + 6 + half, m - 1);
            int r0 = __shfl(myidx, e0), r1 = __shfl(myidx, e1);
            int r2 = __shfl(myidx, e2), r3 = __shfl(myidx, e3);
            uint2 u0 = ((const uint2*)(ef + (size_t)r0 * C))[ch];
            uint2 u1 = ((const uint2*)(ef + (size_t)r1 * C))[ch];
            uint2 u2 = ((const uint2*)(ef + (size_t)r2 * C))[ch];
            uint2 u3 = ((const uint2*)(ef + (size_t)r3 * C))[ch];
            float m0 = (t + 0 + half < m) ? 1.f : 0.f;
            float m1 = (t + 2 + half < m) ? 1.f : 0.f;
            float m2 = (t + 4 + half < m) ? 1.f : 0.f;
            float m3 = (t + 6 + half < m) ? 1.f : 0.f;
            a0 += m0 * bf2f((u16)(u0.x & 0xffffu)) + m1 * bf2f((u16)(u1.x & 0xffffu))
                + m2 * bf2f((u16)(u2.x & 0xffffu)) + m3 * bf2f((u16)(u3.x & 0xffffu));
            a1 += m0 * bf2f((u16)(u0.x >> 16)) + m1 * bf2f((u16)(u1.x >> 16))
                + m2 * bf2f((u16)(u2.x >> 16)) + m3 * bf2f((u16)(u3.x >> 16));
            a2 += m0 * bf2f((u16)(u0.y & 0xffffu)) + m1 * bf2f((u16)(u1.y & 0xffffu))
                + m2 * bf2f((u16)(u2.y & 0xffffu)) + m3 * bf2f((u16)(u3.y & 0xffffu));
            a3 += m0 * bf2f((u16)(u0.y >> 16)) + m1 * bf2f((u16)(u1.y >> 16))
                + m2 * bf2f((u16)(u2.y >> 16)) + m3 * bf2f((u16)(u3.y >> 16));
        }
    }
    a0 += __shfl_xor(a0, 32);
    a1 += __shfl_xor(a1, 32);
    a2 += __shfl_xor(a2, 32);
    a3 += __shfl_xor(a3, 32);
    float sc = deg ? 1.f / (float)deg : 0.f;
    if (lane < 32) {
        float4 bv = *(const float4*)(bias + ch * 4);
        float4 w;
        w.x = a0 * sc + bv.x;
        w.y = a1 * sc + bv.y;
        w.z = a2 * sc + bv.z;
        w.w = a3 * sc + bv.w;
        ((float4*)(out + (size_t)v * C))[ch] = w;
    }
}

extern "C" void kernel_launch(void* const* d_in, const int* in_sizes, int n_in,
                              void* d_out, int out_size, void* d_ws, size_t ws_size,
                              hipStream_t stream) {
    const float* x = (const float*)d_in[0];     // [N_NODES,128] f32
    const int* node_idx = (const int*)d_in[1];  // [2, NNZ] row-major int32
    const int nnz = in_sizes[1] / 2;
    const int* edge_idx = node_idx + nnz;
    const float* W = (const float*)d_in[2];     // [128,128] f32
    const float* bias = (const float*)d_in[3];  // [128] f32
    float* out = (float*)d_out;                 // [N_NODES,128] f32

    int nb1 = (nnz + BCHUNK - 1) / BCHUNK;      // 245 hist/place blocks
    int scanN = NBUCKC * nb1;                   // 287140 count-matrix entries
    int scanBlocks = (scanN + 1023) / 1024;     // 281 (<= 512 for scan_b2)

    // workspace layout (~20.3 MB), all 16B-aligned:
    u16* Wt = (u16*)d_ws;                           // 32 KB
    u16* ef = Wt + 16384;                           // 12.8 MB
    u32* cntM = (u32*)(ef + (size_t)N_EDGES * C);   // scanN u32 (1.15 MB)
    u32* offM = cntM + scanN;                       // scanN u32 (1.15 MB)
    u32* bsum2 = offM + scanN;                      // 512 u32
    uint2* rowinfo = (uint2*)(bsum2 + 512);         // 150000 uint2 (1.2 MB)
    u32* csrC = (u32*)(rowinfo + NCNT);             // 2*nnz u32 (4 MB)

    // d_out (51.2 MB f32) doubles as scratch:
    //   [25.6, 29.6 MB): stage (packed) — written place, consumed bucket_csr
    // node_gather then overwrites the whole buffer with the f32 output.
    u32* stage = (u32*)((char*)d_out + (size_t)N_NODES * C * 2);

    prep_k<<<64 + nb1, 256, 0, stream>>>(W, Wt, node_idx, edge_idx, cntM, nnz, nb1);
    scan_a2<<<scanBlocks, 256, 0, stream>>>(cntM, offM, bsum2, scanN);
    scan_b2<<<1, 256, 0, stream>>>(bsum2, scanBlocks);
    bucket_place_k<<<nb1, 256, 0, stream>>>(node_idx, edge_idx, offM, bsum2,
                                            stage, nnz, nb1);
    bucket_csr_k<<<NBUCKC, 256, 0, stream>>>(offM, bsum2, stage, csrC, rowinfo,
                                             nnz, nb1);
    // fused: gather raw x rows -> LDS G-tile -> MFMA -> ef (3125 blocks x 16 edges)
    edge_gemm_k<<<N_EDGES / 16, 256, 0, stream>>>(x, rowinfo, csrC, Wt, ef);
    node_gather_k<<<(N_NODES + 3) / 4, 256, 0, stream>>>(ef, rowinfo, csrC, bias, out);
}